// Round 14
// baseline (29.152 us; speedup 1.0000x reference)
//
#include <hip/hip_runtime.h>

#define T_DIM 1024
#define B_DIM 32
#define C_DIM 512
#define PROWS 128            // p-rows per block; grid (8,32) = 256 blocks
#define RPW   (PROWS / 4)    // rows per wave = 32

typedef float f32x4 __attribute__((ext_vector_type(4)));

// Wave-specialized fused kernel. One block = one batch b, 128 p-rows.
//   wave 0 : solo preamble — label scan (16 labels/lane), compaction, means
//            (4 rows/round), prefix-product scale (R8-validated) -> sscale[],
//            threadfence, flag=1; then streams its own 32 rows (late).
//   waves 1-3 : prefetch 2 chunks (32 f32x4) of audio immediately, poll flag,
//            then store/load/store rotation. Loads are never gated by scale.
__global__ __launch_bounds__(256) void k_fused(const float* __restrict__ video,
                                               const float* __restrict__ audio,
                                               const int* __restrict__ labels,
                                               float* __restrict__ out) {
    int b     = blockIdx.y;
    int pBase = blockIdx.x * PROWS;
    int tid   = threadIdx.x;
    int lane  = tid & 63;
    int wave  = tid >> 6;

    __shared__ float vm[T_DIM];
    __shared__ int   pos[T_DIM];
    __shared__ float pre[T_DIM + 1];
    __shared__ float rpre[T_DIM + 1];
    __shared__ float sscale[PROWS];
    __shared__ int   flag;

    if (tid == 0) flag = 0;
    __syncthreads();                       // only barrier in the kernel

    if (wave == 0) {
        // ---- solo label scan: 16 labels per lane ----
        const int* lb = labels + b * T_DIM + lane * 16;
        int4 l0 = *(const int4*)(lb + 0),  l1 = *(const int4*)(lb + 4);
        int4 l2 = *(const int4*)(lb + 8),  l3 = *(const int4*)(lb + 12);
        int labv[16] = {l0.x,l0.y,l0.z,l0.w, l1.x,l1.y,l1.z,l1.w,
                        l2.x,l2.y,l2.z,l2.w, l3.x,l3.y,l3.z,l3.w};
        int cnt = 0;
        #pragma unroll
        for (int j = 0; j < 16; ++j) cnt += (labv[j] == 1);
        int incl = cnt;
        #pragma unroll
        for (int off = 1; off < 64; off <<= 1) {
            int n = __shfl_up(incl, off);
            if (lane >= off) incl += n;
        }
        int t    = __shfl(incl, 63);
        int rank = incl - cnt;
        #pragma unroll
        for (int j = 0; j < 16; ++j)
            if (labv[j] == 1) pos[rank++] = lane * 16 + j;

        // ---- means of labeled rows, 4 rows per round ----
        for (int base = 0; base < t; base += 4) {
            int i1 = base + 1, i2 = base + 2, i3 = base + 3;
            int q0 = pos[base];
            int q1 = (i1 < t) ? pos[i1] : q0;
            int q2 = (i2 < t) ? pos[i2] : q0;
            int q3 = (i3 < t) ? pos[i3] : q0;
            const float* r0 = video + (size_t)q0 * (B_DIM * C_DIM) + b * C_DIM;
            const float* r1 = video + (size_t)q1 * (B_DIM * C_DIM) + b * C_DIM;
            const float* r2 = video + (size_t)q2 * (B_DIM * C_DIM) + b * C_DIM;
            const float* r3 = video + (size_t)q3 * (B_DIM * C_DIM) + b * C_DIM;
            float4 x0a = *(const float4*)(r0 + lane * 4), x0b = *(const float4*)(r0 + 256 + lane * 4);
            float4 x1a = *(const float4*)(r1 + lane * 4), x1b = *(const float4*)(r1 + 256 + lane * 4);
            float4 x2a = *(const float4*)(r2 + lane * 4), x2b = *(const float4*)(r2 + 256 + lane * 4);
            float4 x3a = *(const float4*)(r3 + lane * 4), x3b = *(const float4*)(r3 + 256 + lane * 4);
            float v0 = x0a.x+x0a.y+x0a.z+x0a.w + x0b.x+x0b.y+x0b.z+x0b.w;
            float v1 = x1a.x+x1a.y+x1a.z+x1a.w + x1b.x+x1b.y+x1b.z+x1b.w;
            float v2 = x2a.x+x2a.y+x2a.z+x2a.w + x2b.x+x2b.y+x2b.z+x2b.w;
            float v3 = x3a.x+x3a.y+x3a.z+x3a.w + x3b.x+x3b.y+x3b.z+x3b.w;
            #pragma unroll
            for (int off = 32; off; off >>= 1) {
                v0 += __shfl_xor(v0, off);
                v1 += __shfl_xor(v1, off);
                v2 += __shfl_xor(v2, off);
                v3 += __shfl_xor(v3, off);
            }
            if (lane == 0) {
                vm[base] = v0 * (1.0f / C_DIM);
                if (i1 < t) vm[i1] = v1 * (1.0f / C_DIM);
                if (i2 < t) vm[i2] = v2 * (1.0f / C_DIM);
                if (i3 < t) vm[i3] = v3 * (1.0f / C_DIM);
            }
        }

        // ---- prefix products + reciprocals (R8-validated) ----
        float carry = 1.0f;
        for (int b2 = 0; b2 < t; b2 += 64) {
            int k = b2 + lane;
            float scv = (k < t) ? vm[k] : 1.0f;
            #pragma unroll
            for (int off = 1; off < 64; off <<= 1) {
                float n = __shfl_up(scv, off);
                if (lane >= off) scv *= n;
            }
            if (k < t) {
                float pk = carry * scv;
                pre[k + 1]  = pk;
                rpre[k + 1] = 1.0f / pk;
            }
            carry *= __shfl(scv, 63);
        }
        if (lane == 0) { pre[0] = 1.0f; rpre[0] = 1.0f; }

        // ---- sscale for this block's 128 rows (2 per lane) ----
        #pragma unroll
        for (int q = 0; q < 2; ++q) {
            int rl = q * 64 + lane;
            int p  = pBase + rl;
            int lo = p - (T_DIM - t); if (lo < 0) lo = 0;
            int hi = p < (t - 1) ? p : (t - 1);
            sscale[rl] = (lo <= hi) ? pre[hi + 1] * rpre[lo] : 1.0f;
        }
        __threadfence_block();
        if (lane == 0) *(volatile int*)&flag = 1;
    }

    // ---- streaming: wave w owns rows pBase + w*32 + 0..31 ----
    const f32x4* ain  = (const f32x4*)audio;
    f32x4*       aout = (f32x4*)out;
    int row0 = wave * RPW;
    size_t gb = ((size_t)(pBase + row0) * B_DIM + b) * (C_DIM / 4) + lane;
    const int rst = B_DIM * (C_DIM / 4);   // f32x4 stride between p-rows

    // prefetch chunks 0 and 1 (rows 0..15): 32 f32x4 in flight per thread
    f32x4 va[16], vb[16];
    #pragma unroll
    for (int r = 0; r < 8; ++r) {
        size_t bi = gb + (size_t)r * rst;
        va[2*r] = ain[bi]; va[2*r+1] = ain[bi + 64];
    }
    #pragma unroll
    for (int r = 0; r < 8; ++r) {
        size_t bi = gb + (size_t)(8 + r) * rst;
        vb[2*r] = ain[bi]; vb[2*r+1] = ain[bi + 64];
    }
    asm volatile("" ::: "memory");         // pin prefetch before the poll

    if (wave != 0) {
        while (*(volatile int*)&flag == 0) __builtin_amdgcn_s_sleep(2);
    }
    __threadfence_block();                 // acquire: sscale reads stay below

    // store chunk0, load chunk2 into va
    #pragma unroll
    for (int r = 0; r < 8; ++r) {
        float s = sscale[row0 + r];
        size_t bi = gb + (size_t)r * rst;
        aout[bi] = va[2*r] * s; aout[bi + 64] = va[2*r+1] * s;
    }
    #pragma unroll
    for (int r = 0; r < 8; ++r) {
        size_t bi = gb + (size_t)(16 + r) * rst;
        va[2*r] = ain[bi]; va[2*r+1] = ain[bi + 64];
    }
    // store chunk1, load chunk3 into vb
    #pragma unroll
    for (int r = 0; r < 8; ++r) {
        float s = sscale[row0 + 8 + r];
        size_t bi = gb + (size_t)(8 + r) * rst;
        aout[bi] = vb[2*r] * s; aout[bi + 64] = vb[2*r+1] * s;
    }
    #pragma unroll
    for (int r = 0; r < 8; ++r) {
        size_t bi = gb + (size_t)(24 + r) * rst;
        vb[2*r] = ain[bi]; vb[2*r+1] = ain[bi + 64];
    }
    // store chunk2
    #pragma unroll
    for (int r = 0; r < 8; ++r) {
        float s = sscale[row0 + 16 + r];
        size_t bi = gb + (size_t)(16 + r) * rst;
        aout[bi] = va[2*r] * s; aout[bi + 64] = va[2*r+1] * s;
    }
    // store chunk3
    #pragma unroll
    for (int r = 0; r < 8; ++r) {
        float s = sscale[row0 + 24 + r];
        size_t bi = gb + (size_t)(24 + r) * rst;
        aout[bi] = vb[2*r] * s; aout[bi + 64] = vb[2*r+1] * s;
    }
}

extern "C" void kernel_launch(void* const* d_in, const int* in_sizes, int n_in,
                              void* d_out, int out_size, void* d_ws, size_t ws_size,
                              hipStream_t stream) {
    const float* video  = (const float*)d_in[0];
    const float* audio  = (const float*)d_in[1];
    const int*   labels = (const int*)d_in[2];
    float* out = (float*)d_out;

    dim3 grid(T_DIM / PROWS, B_DIM);
    k_fused<<<grid, 256, 0, stream>>>(video, audio, labels, out);
}

// Round 15
// 26.692 us; speedup vs baseline: 1.0922x; 1.0922x over previous
//
#include <hip/hip_runtime.h>

#define T_DIM 1024
#define B_DIM 32
#define C_DIM 512
#define PROWS 64   // best-known (R12): 512 blocks, 2 per CU

typedef float f32x4 __attribute__((ext_vector_type(4)));

// R12 skeleton, single change: phase-B means in ONE latency round
// (4 rows per wave per round; t<=16 -> 1 round) per R9's validated pattern.
__global__ __launch_bounds__(256) void k_fused(const float* __restrict__ video,
                                               const float* __restrict__ audio,
                                               const int* __restrict__ labels,
                                               float* __restrict__ out) {
    int b     = blockIdx.y;
    int pBase = blockIdx.x * PROWS;
    int tid   = threadIdx.x;
    int lane  = tid & 63;
    int wave  = tid >> 6;
    __shared__ float vm[T_DIM];
    __shared__ int   pos[T_DIM];
    __shared__ int   waveTot[4];
    __shared__ float sscale[PROWS];

    // streaming geometry: thread handles rows k = 2*i + half, i = 0..31
    int half = tid >> 7;
    int c4   = tid & 127;
    const int rstep = 2 * B_DIM * (C_DIM / 4);
    int base0 = ((pBase + half) * B_DIM + b) * (C_DIM / 4) + c4;
    const f32x4* ain  = (const f32x4*)audio;
    f32x4*       aout = (f32x4*)out;

    // ---- phase A: prefetch first 2 audio rows + labels together ----
    f32x4 a[32];
    a[0] = ain[base0];
    a[1] = ain[base0 + rstep];
    int4 lv = *(const int4*)(labels + b * T_DIM + tid * 4);

    int p0 = tid * 4;
    int f0 = (lv.x == 1), f1 = (lv.y == 1), f2 = (lv.z == 1), f3 = (lv.w == 1);
    int cnt = f0 + f1 + f2 + f3;

    int incl = cnt;
    #pragma unroll
    for (int off = 1; off < 64; off <<= 1) {
        int n = __shfl_up(incl, off);
        if (lane >= off) incl += n;
    }
    if (lane == 63) waveTot[wave] = incl;
    __syncthreads();

    int waveOff = 0;
    for (int w = 0; w < wave; ++w) waveOff += waveTot[w];
    int t = waveTot[0] + waveTot[1] + waveTot[2] + waveTot[3];
    int r = waveOff + incl - cnt;

    if (f0) pos[r++] = p0 + 0;
    if (f1) pos[r++] = p0 + 1;
    if (f2) pos[r++] = p0 + 2;
    if (f3) pos[r++] = p0 + 3;
    __syncthreads();

    // ---- phase B: means, 4 rows per wave per round (1 round for t<=16) ----
    for (int base = 0; base < t; base += 16) {
        int rr0 = base + wave;
        int rr1 = rr0 + 4, rr2 = rr0 + 8, rr3 = rr0 + 12;
        int rc0 = rr0 < t ? rr0 : 0;
        int rc1 = rr1 < t ? rr1 : 0;
        int rc2 = rr2 < t ? rr2 : 0;
        int rc3 = rr3 < t ? rr3 : 0;
        const float* s0p = video + (size_t)pos[rc0] * (B_DIM * C_DIM) + b * C_DIM;
        const float* s1p = video + (size_t)pos[rc1] * (B_DIM * C_DIM) + b * C_DIM;
        const float* s2p = video + (size_t)pos[rc2] * (B_DIM * C_DIM) + b * C_DIM;
        const float* s3p = video + (size_t)pos[rc3] * (B_DIM * C_DIM) + b * C_DIM;
        float4 x0a = *(const float4*)(s0p + lane * 4);
        float4 x0b = *(const float4*)(s0p + 256 + lane * 4);
        float4 x1a = *(const float4*)(s1p + lane * 4);
        float4 x1b = *(const float4*)(s1p + 256 + lane * 4);
        float4 x2a = *(const float4*)(s2p + lane * 4);
        float4 x2b = *(const float4*)(s2p + 256 + lane * 4);
        float4 x3a = *(const float4*)(s3p + lane * 4);
        float4 x3b = *(const float4*)(s3p + 256 + lane * 4);
        float v0 = x0a.x + x0a.y + x0a.z + x0a.w + x0b.x + x0b.y + x0b.z + x0b.w;
        float v1 = x1a.x + x1a.y + x1a.z + x1a.w + x1b.x + x1b.y + x1b.z + x1b.w;
        float v2 = x2a.x + x2a.y + x2a.z + x2a.w + x2b.x + x2b.y + x2b.z + x2b.w;
        float v3 = x3a.x + x3a.y + x3a.z + x3a.w + x3b.x + x3b.y + x3b.z + x3b.w;
        #pragma unroll
        for (int off = 32; off; off >>= 1) {
            v0 += __shfl_xor(v0, off);
            v1 += __shfl_xor(v1, off);
            v2 += __shfl_xor(v2, off);
            v3 += __shfl_xor(v3, off);
        }
        if (lane == 0) {
            if (rr0 < t) vm[rr0] = v0 * (1.0f / C_DIM);
            if (rr1 < t) vm[rr1] = v1 * (1.0f / C_DIM);
            if (rr2 < t) vm[rr2] = v2 * (1.0f / C_DIM);
            if (rr3 < t) vm[rr3] = v3 * (1.0f / C_DIM);
        }
    }
    __syncthreads();

    // ---- phase C: issue remaining 30 audio rows, then windowed product ----
    #pragma unroll
    for (int i = 2; i < 32; ++i)
        a[i] = ain[base0 + i * rstep];

    if (tid < PROWS) {
        int p  = pBase + tid;
        int lo = p - (T_DIM - t); if (lo < 0) lo = 0;
        int hi = p < (t - 1) ? p : (t - 1);
        float s = 1.0f;
        for (int m = lo; m <= hi; ++m) s *= vm[m];
        sscale[tid] = s;
    }
    __syncthreads();

    // ---- phase D: mul + store burst ----
    #pragma unroll
    for (int i = 0; i < 32; ++i) {
        float s = sscale[2 * i + half];
        aout[base0 + i * rstep] = a[i] * s;
    }
}

extern "C" void kernel_launch(void* const* d_in, const int* in_sizes, int n_in,
                              void* d_out, int out_size, void* d_ws, size_t ws_size,
                              hipStream_t stream) {
    const float* video  = (const float*)d_in[0];
    const float* audio  = (const float*)d_in[1];
    const int*   labels = (const int*)d_in[2];
    float* out = (float*)d_out;

    dim3 grid(T_DIM / PROWS, B_DIM);
    k_fused<<<grid, 256, 0, stream>>>(video, audio, labels, out);
}